// Round 2
// baseline (1317.367 us; speedup 1.0000x reference)
//
#include <hip/hip_runtime.h>
#include <math.h>

// Dims (fixed by setup_inputs): B=4, N=2048, C1=64, C2=128, P=1024, Q=16, L=64, V=64, OUT=40
// BN = B*N = 8192, QP = Q*P = 16384
#define BN_EPS 1e-5f

typedef __attribute__((ext_vector_type(8))) _Float16 half8;
typedef __attribute__((ext_vector_type(4))) _Float16 half4;
typedef __attribute__((ext_vector_type(4))) float f32x4;
#define SPLIT_S  2048.0f
#define INV_S    (1.0f/2048.0f)

// DIAGNOSTIC ROUND: k_caps / k_uhat / k_route(pass0) are launched with an extra
// blockIdx.z replication factor (4x / 5x / 8x). All three are idempotent
// (deterministic writes), so replicas write identical bytes; outputs unchanged.
// Purpose: push them past the ~161us fill dispatches into the rocprof top-5
// so we finally see their per-kernel durations + counters.

// ---------------------------------------------------------------- conv1 + batch stats fused.
__global__ __launch_bounds__(256) void k_conv1stats(const float* __restrict__ x,
        const float* __restrict__ w1, float* __restrict__ y1,
        float* __restrict__ mean, float* __restrict__ inv) {
    const int o = blockIdx.x, t = threadIdx.x;
    const float wa = w1[o*3+0], wb = w1[o*3+1], wc = w1[o*3+2];
    float s = 0.f, ss = 0.f;
#pragma unroll
    for (int it = 0; it < 8; ++it) {
        int i = it * 256 + t;                      // 0..2047 : bn/4
        int b = i >> 9, n4 = (i & 511) * 4;
        const float* xb = x + (size_t)b * 6144 + n4;
        float4 x0 = *(const float4*)(xb);
        float4 x1 = *(const float4*)(xb + 2048);
        float4 x2 = *(const float4*)(xb + 4096);
        float4 r;
        r.x = wa*x0.x + wb*x1.x + wc*x2.x;
        r.y = wa*x0.y + wb*x1.y + wc*x2.y;
        r.z = wa*x0.z + wb*x1.z + wc*x2.z;
        r.w = wa*x0.w + wb*x1.w + wc*x2.w;
        *(float4*)(y1 + o * 8192 + i * 4) = r;
        s += r.x + r.y + r.z + r.w;
        ss = fmaf(r.x, r.x, fmaf(r.y, r.y, fmaf(r.z, r.z, fmaf(r.w, r.w, ss))));
    }
    __shared__ float rs[256], rss[256];
    rs[t] = s; rss[t] = ss;
    __syncthreads();
    for (int off = 128; off > 0; off >>= 1) {
        if (t < off) { rs[t] += rs[t+off]; rss[t] += rss[t+off]; }
        __syncthreads();
    }
    if (t == 0) {
        float m = rs[0] * (1.f/8192.f);
        float var = rss[0] * (1.f/8192.f) - m*m;
        mean[o] = m;
        inv[o]  = rsqrtf(var + BN_EPS);
    }
}

// ---------------------------------------------------------------- per-channel batch stats (for y2)
__global__ void k_stats(const float* __restrict__ y, float* __restrict__ mean,
                        float* __restrict__ inv) {
    int c = blockIdx.x, t = threadIdx.x;
    float s = 0.f, ss = 0.f;
    const float4* src = (const float4*)(y + c * 8192);
    for (int i = t; i < 2048; i += 256) {
        float4 v = src[i];
        s += v.x + v.y + v.z + v.w;
        ss = fmaf(v.x, v.x, fmaf(v.y, v.y, fmaf(v.z, v.z, fmaf(v.w, v.w, ss))));
    }
    __shared__ float rs[256], rss[256];
    rs[t] = s; rss[t] = ss;
    __syncthreads();
    for (int off = 128; off > 0; off >>= 1) {
        if (t < off) { rs[t] += rs[t+off]; rss[t] += rss[t+off]; }
        __syncthreads();
    }
    if (t == 0) {
        float m = rs[0] * (1.f/8192.f);
        float var = rss[0] * (1.f/8192.f) - m*m;
        mean[c] = m;
        inv[c]  = rsqrtf(var + BN_EPS);
    }
}

// ---------------------------------------------------------------- conv2 with BN1+ReLU fused on load
__global__ __launch_bounds__(256) void k_conv2(const float* __restrict__ y1,
        const float* __restrict__ w2,
        const float* __restrict__ mean1, const float* __restrict__ inv1,
        const float* __restrict__ g1, const float* __restrict__ be1,
        float* __restrict__ y2) {
    __shared__ float sc1[64], sh1[64];
    const int t = threadIdx.x;
    if (t < 64) {
        float sc = inv1[t] * g1[t];
        sc1[t] = sc;
        sh1[t] = be1[t] - mean1[t] * sc;
    }
    __syncthreads();
    int bn0 = (blockIdx.x * 256 + t) * 4;
    int og0 = blockIdx.y * 4;
    float4 acc[4];
#pragma unroll
    for (int j = 0; j < 4; ++j) acc[j] = float4{0.f,0.f,0.f,0.f};
    for (int c = 0; c < 64; ++c) {
        float4 hv = *(const float4*)(y1 + c*8192 + bn0);
        float sc = sc1[c], sh = sh1[c];
        hv.x = fmaxf(fmaf(hv.x, sc, sh), 0.f);
        hv.y = fmaxf(fmaf(hv.y, sc, sh), 0.f);
        hv.z = fmaxf(fmaf(hv.z, sc, sh), 0.f);
        hv.w = fmaxf(fmaf(hv.w, sc, sh), 0.f);
#pragma unroll
        for (int j = 0; j < 4; ++j) {
            float w = w2[(og0+j)*64 + c];
            acc[j].x = fmaf(w, hv.x, acc[j].x); acc[j].y = fmaf(w, hv.y, acc[j].y);
            acc[j].z = fmaf(w, hv.z, acc[j].z); acc[j].w = fmaf(w, hv.w, acc[j].w);
        }
    }
#pragma unroll
    for (int j = 0; j < 4; ++j) *(float4*)(y2 + (og0+j)*8192 + bn0) = acc[j];
}

// ---------------------------------------------------------------- split w3 fp32 -> fp16 hi + scaled lo
__global__ void k_split_w3(const float* __restrict__ w, const float* __restrict__ g3,
                           _Float16* __restrict__ hi, _Float16* __restrict__ lo) {
    int base = blockIdx.x * 256 + threadIdx.x;     // 4 chunks
#pragma unroll
    for (int it = 0; it < 4; ++it) {
        int i = (base + it * 131072) * 4;          // element index
        float4 d = *reinterpret_cast<const float4*>(w + i);
        float sgn = (g3[i >> 7] < 0.f) ? -1.f : 1.f;
        float vs[4] = {d.x * sgn, d.y * sgn, d.z * sgn, d.w * sgn};
        half4 h4, l4;
#pragma unroll
        for (int j = 0; j < 4; ++j) {
            _Float16 h = (_Float16)vs[j];
            h4[j] = h;
            l4[j] = (_Float16)((vs[j] - (float)h) * SPLIT_S);
        }
        *reinterpret_cast<half4*>(hi + i) = h4;
        *reinterpret_cast<half4*>(lo + i) = l4;
    }
}

// ---------------------------------------------------------------- BN2+ReLU fused with transpose+split
__global__ __launch_bounds__(256) void k_h2t_split(const float* __restrict__ y2,
        const float* __restrict__ mean, const float* __restrict__ inv,
        const float* __restrict__ g, const float* __restrict__ be,
        _Float16* __restrict__ hi, _Float16* __restrict__ lo) {
    __shared__ float tile[64][65];
    const int t = threadIdx.x;
    const int bn0 = blockIdx.x * 64, c0 = blockIdx.y * 64;
#pragma unroll
    for (int r = 0; r < 4; ++r) {
        int idx = r * 256 + t;                     // 0..1023, 4 elems each
        int cl = idx >> 4, bn4 = (idx & 15) * 4;
        int c = c0 + cl;
        float sc = inv[c] * g[c];
        float sh = be[c] - mean[c] * sc;
        float4 d = *(const float4*)(y2 + (size_t)c * 8192 + bn0 + bn4);
        tile[cl][bn4  ] = fmaxf(fmaf(d.x, sc, sh), 0.f);
        tile[cl][bn4+1] = fmaxf(fmaf(d.y, sc, sh), 0.f);
        tile[cl][bn4+2] = fmaxf(fmaf(d.z, sc, sh), 0.f);
        tile[cl][bn4+3] = fmaxf(fmaf(d.w, sc, sh), 0.f);
    }
    __syncthreads();
#pragma unroll
    for (int r = 0; r < 4; ++r) {
        int idx = r * 256 + t;
        int bnl = idx >> 4, c4 = (idx & 15) * 4;
        half4 h4, l4;
#pragma unroll
        for (int j = 0; j < 4; ++j) {
            float v = tile[c4 + j][bnl];
            _Float16 h = (_Float16)v;
            h4[j] = h;
            l4[j] = (_Float16)((v - (float)h) * SPLIT_S);
        }
        size_t o = (size_t)(bn0 + bnl) * 128 + c0 + c4;
        *reinterpret_cast<half4*>(hi + o) = h4;
        *reinterpret_cast<half4*>(lo + o) = l4;
    }
}

// ---------------------------------------------------------------- THE BIG ONE v6 (probe x4 via blockIdx.z).
__global__ __launch_bounds__(256, 2) void k_caps(
        const _Float16* __restrict__ w3h, const _Float16* __restrict__ w3l,
        const _Float16* __restrict__ h2h, const _Float16* __restrict__ h2l,
        float* __restrict__ umax,
        float* __restrict__ usum_b, float* __restrict__ usumsq_b) {
    const int lane = threadIdx.x & 63, wave = threadIdx.x >> 6;
    const int b = blockIdx.y;
    const int mrow = blockIdx.x * 128 + wave * 32;
    const int r16 = lane & 15, kq = lane >> 4;     // frag: row/col=lane&15, k=kq*8+j

    __shared__ _Float16 Bs[2][2][8][64][8];        // [buf][g][ks*2+h][lane][j] 32 KB

    half8 Ah[2][4], Al[2][4];
#pragma unroll
    for (int mt = 0; mt < 2; ++mt) {
        const size_t base = (size_t)(mrow + mt*16 + r16) * 128 + kq * 8;
#pragma unroll
        for (int ks = 0; ks < 4; ++ks) {
            Ah[mt][ks] = *reinterpret_cast<const half8*>(w3h + base + ks*32);
            Al[mt][ks] = *reinterpret_cast<const half8*>(w3l + base + ks*32);
        }
    }
    float mx[2][4], sm[2][4], sq[2][4];
#pragma unroll
    for (int mt = 0; mt < 2; ++mt)
#pragma unroll
        for (int r = 0; r < 4; ++r) {
            mx[mt][r] = -3.4e38f; sm[mt][r] = 0.f; sq[mt][r] = 0.f;
        }

    const int u0 = wave * 2;
    const size_t srow = (size_t)(b*2048 + r16) * 128 + wave * 32 + kq * 8;

    { // prologue: stage nt=0 into buf 0
#pragma unroll
        for (int g = 0; g < 2; ++g) {
            const size_t a = srow + (size_t)g * 16 * 128;
            *reinterpret_cast<half8*>(&Bs[0][g][u0  ][lane][0]) = *reinterpret_cast<const half8*>(h2h + a);
            *reinterpret_cast<half8*>(&Bs[0][g][u0+1][lane][0]) = *reinterpret_cast<const half8*>(h2l + a);
        }
    }
    __syncthreads();

    for (int nt = 0; nt < 64; ++nt) {              // 32 cols per iter
        const int buf = nt & 1;
        const int ntn = (nt + 1 < 64) ? nt + 1 : nt;
        const size_t snext = srow + (size_t)ntn * 32 * 128;
        half8 g0h = *reinterpret_cast<const half8*>(h2h + snext);
        half8 g0l = *reinterpret_cast<const half8*>(h2l + snext);
        half8 g1h = *reinterpret_cast<const half8*>(h2h + snext + 2048);
        half8 g1l = *reinterpret_cast<const half8*>(h2l + snext + 2048);

#pragma unroll
        for (int g = 0; g < 2; ++g) {
            f32x4 acc[2], accx[2];
#pragma unroll
            for (int mt = 0; mt < 2; ++mt) { acc[mt] = f32x4{0.f,0.f,0.f,0.f}; accx[mt] = f32x4{0.f,0.f,0.f,0.f}; }
#pragma unroll
            for (int ks = 0; ks < 4; ++ks) {
                half8 Bh = *reinterpret_cast<const half8*>(&Bs[buf][g][ks*2  ][lane][0]);
                half8 Bl = *reinterpret_cast<const half8*>(&Bs[buf][g][ks*2+1][lane][0]);
#pragma unroll
                for (int mt = 0; mt < 2; ++mt) {
                    acc[mt]  = __builtin_amdgcn_mfma_f32_16x16x32_f16(Ah[mt][ks], Bh, acc[mt], 0, 0, 0);
                    accx[mt] = __builtin_amdgcn_mfma_f32_16x16x32_f16(Ah[mt][ks], Bl, accx[mt], 0, 0, 0);
                    accx[mt] = __builtin_amdgcn_mfma_f32_16x16x32_f16(Al[mt][ks], Bh, accx[mt], 0, 0, 0);
                }
            }
#pragma unroll
            for (int mt = 0; mt < 2; ++mt)
#pragma unroll
                for (int r = 0; r < 4; ++r) {
                    float v = fmaf(accx[mt][r], INV_S, acc[mt][r]);
                    mx[mt][r] = fmaxf(mx[mt][r], v);
                    sm[mt][r] += v;
                    sq[mt][r] = fmaf(v, v, sq[mt][r]);
                }
        }
        *reinterpret_cast<half8*>(&Bs[buf^1][0][u0  ][lane][0]) = g0h;
        *reinterpret_cast<half8*>(&Bs[buf^1][0][u0+1][lane][0]) = g0l;
        *reinterpret_cast<half8*>(&Bs[buf^1][1][u0  ][lane][0]) = g1h;
        *reinterpret_cast<half8*>(&Bs[buf^1][1][u0+1][lane][0]) = g1l;
        __syncthreads();
    }

    // reduce over the 16 column lanes (C/D: col=lane&15, row=kq*4+reg)
#pragma unroll
    for (int off = 8; off >= 1; off >>= 1)
#pragma unroll
        for (int mt = 0; mt < 2; ++mt)
#pragma unroll
            for (int r = 0; r < 4; ++r) {
                mx[mt][r] = fmaxf(mx[mt][r], __shfl_xor(mx[mt][r], off));
                sm[mt][r] += __shfl_xor(sm[mt][r], off);
                sq[mt][r] += __shfl_xor(sq[mt][r], off);
            }
    if (r16 == 0) {
#pragma unroll
        for (int mt = 0; mt < 2; ++mt)
#pragma unroll
            for (int r = 0; r < 4; ++r) {
                int qp = mrow + mt*16 + kq*4 + r;
                umax[b*16384 + qp]     = mx[mt][r];
                usum_b[b*16384 + qp]   = sm[mt][r];
                usumsq_b[b*16384 + qp] = sq[mt][r];
            }
    }
}

// ---------------------------------------------------------------- BN3 (analytic, sign-folded) + squash over Q
__global__ void k_u(const float* __restrict__ umax,
                    const float* __restrict__ usum_b, const float* __restrict__ usumsq_b,
                    const float* __restrict__ g3, const float* __restrict__ be3,
                    float* __restrict__ u) {
    int tg = blockIdx.x * 256 + threadIdx.x;       // 0..4095 : (b,p)
    int b = tg >> 10, p = tg & 1023;
    float ub[16]; float sn = 0.f;
#pragma unroll
    for (int q = 0; q < 16; ++q) {
        int qp = q * 1024 + p;
        float s  = usum_b[qp] + usum_b[16384+qp] + usum_b[32768+qp] + usum_b[49152+qp];
        float ss = usumsq_b[qp] + usumsq_b[16384+qp] + usumsq_b[32768+qp] + usumsq_b[49152+qp];
        float g  = g3[qp];
        float sgn = (g < 0.f) ? -1.f : 1.f;
        float mean  = sgn * s * (1.f/8192.f);                 // un-fold sign
        float var   = ss * (1.f/8192.f) - mean*mean;
        float scale = g * rsqrtf(var + BN_EPS);
        float val = sgn * umax[b*16384 + qp];                 // max u (g>=0) or min u (g<0)
        float vb = (val - mean) * scale + be3[qp];
        ub[q] = vb; sn = fmaf(vb, vb, sn);
    }
    float f = sqrtf(sn) / (1.f + sn);              // squash factor
#pragma unroll
    for (int q = 0; q < 16; ++q) u[tg*16 + q] = ub[q] * f;
}

// ---------------------------------------------------------------- u_hat + fused p-partial sums (probe x5 via blockIdx.z).
__global__ __launch_bounds__(256) void k_uhat(const float* __restrict__ Wr,
                                              const float* __restrict__ u,
                                              float* __restrict__ uhat2,
                                              float* __restrict__ s1p) {
    const int t = threadIdx.x;
    const int pblk = blockIdx.x, l = blockIdx.y;
    __shared__ float wr[4][64][20];                // [p][v][q] q-contiguous, padded
    __shared__ float us[4][4][16];                 // [p][b][q]
    const int bb = t >> 6, v = t & 63;
    float s1acc = 0.f;
    for (int sub = 0; sub < 8; ++sub) {
        const int p0 = pblk * 32 + sub * 4;
        const float* src = Wr + ((size_t)l * 1024 + p0) * 1024;
        if (sub) __syncthreads();                  // LDS reuse guard
#pragma unroll
        for (int it = 0; it < 4; ++it) {
            float4 d = *(const float4*)(src + (it*256 + t) * 4);
            int vv = t >> 2, q0 = (t & 3) * 4;     // p = it
            *(float4*)&wr[it][vv][q0] = d;
        }
        {
            int p = t >> 6, b2 = (t >> 4) & 3, q = t & 15;
            us[p][b2][q] = u[((size_t)b2 * 1024 + p0 + p) * 16 + q];
        }
        __syncthreads();
#pragma unroll
        for (int p = 0; p < 4; ++p) {
            float acc = 0.f;
#pragma unroll
            for (int q4 = 0; q4 < 4; ++q4) {
                float4 wf = *(const float4*)&wr[p][v][q4*4];
                float4 uf = *(const float4*)&us[p][bb][q4*4];
                acc = fmaf(wf.x, uf.x, acc);
                acc = fmaf(wf.y, uf.y, acc);
                acc = fmaf(wf.z, uf.z, acc);
                acc = fmaf(wf.w, uf.w, acc);
            }
            uhat2[(((size_t)bb * 1024 + p0 + p) * 64 + l) * 64 + v] = acc;
            s1acc += acc;
        }
    }
    s1p[(((size_t)pblk * 4 + bb) * 64 + l) * 64 + v] = s1acc;
}

// ---------------------------------------------------------------- reduce s1 partials + squash -> v1
__global__ void k_s1red(const float* __restrict__ s1p, float* __restrict__ vout) {
    const int wv = blockIdx.x;                      // b*64 + l
    const int b = wv >> 6, l = wv & 63;
    const int v = threadIdx.x;
    float acc = 0.f;
#pragma unroll
    for (int pblk = 0; pblk < 32; ++pblk)
        acc += s1p[(((size_t)pblk * 4 + b) * 64 + l) * 64 + v];
    float s = acc * (1.f/64.f);
    float sn = s * s;
#pragma unroll
    for (int off = 32; off >= 1; off >>= 1) sn += __shfl_xor(sn, off);
    vout[wv * 64 + v] = s * sqrtf(sn) / (1.f + sn);
}

// ---------------------------------------------------------------- routing pass (B or C) (pass0 probe x8 via blockIdx.z).
__global__ __launch_bounds__(256) void k_route(const float* __restrict__ uhat2,
                                               const float* __restrict__ vin,
                                               float* __restrict__ bij,
                                               float* __restrict__ part, const int read_b) {
    const int blk = blockIdx.x;
    const int b = blk >> 7, ch = blk & 127;
    const int p0 = ch * 8;
    const int t = threadIdx.x;
    const int v = t & 63, w = t >> 6;
    __shared__ float uh[64][68];
    __shared__ float vs[64][68];
    __shared__ float bl[64];
    {
        const float* src = vin + b * 4096;
        for (int i = t; i < 1024; i += 256) {
            float4 d = *(const float4*)(src + i * 4);
            int l = i >> 4, v0 = (i & 15) * 4;
            vs[l][v0] = d.x; vs[l][v0+1] = d.y; vs[l][v0+2] = d.z; vs[l][v0+3] = d.w;
        }
    }
    float sacc[16];
#pragma unroll
    for (int j = 0; j < 16; ++j) sacc[j] = 0.f;

    for (int pp = 0; pp < 8; ++pp) {
        const int p = p0 + pp;
        __syncthreads();                            // uh/bl reuse guard (covers vs on pp=0)
        const float* src = uhat2 + ((size_t)b * 1024 + p) * 4096;   // contiguous 16 KB
        for (int i = t; i < 1024; i += 256) {
            float4 d = *(const float4*)(src + i * 4);
            int l = i >> 4, v0 = (i & 15) * 4;
            uh[l][v0] = d.x; uh[l][v0+1] = d.y; uh[l][v0+2] = d.z; uh[l][v0+3] = d.w;
        }
        __syncthreads();
#pragma unroll
        for (int i = 0; i < 16; ++i) {
            const int l = w * 16 + i;
            float prod = uh[l][v] * vs[l][v];
#pragma unroll
            for (int off = 32; off >= 1; off >>= 1) prod += __shfl_xor(prod, off);
            if (v == 0) {
                float bb = prod;
                if (read_b) bb += bij[(b * 64 + l) * 1024 + p];
                bl[l] = bb;
                if (!read_b) bij[(b * 64 + l) * 1024 + p] = bb;
            }
        }
        __syncthreads();
        // all-wave softmax over l, in registers: lane v holds x[l=v]
        float xv = bl[v];
        float m = xv;
#pragma unroll
        for (int off = 32; off >= 1; off >>= 1) m = fmaxf(m, __shfl_xor(m, off));
        float e = expf(xv - m);
        float sgm = e;
#pragma unroll
        for (int off = 32; off >= 1; off >>= 1) sgm += __shfl_xor(sgm, off);
        float c = e / sgm;                          // c[l=v]
#pragma unroll
        for (int j = 0; j < 16; ++j) {
            const int l = j * 4 + w;
            float cl = __shfl(c, l);
            sacc[j] = fmaf(cl, uh[l][v], sacc[j]);
        }
    }
#pragma unroll
    for (int j = 0; j < 16; ++j) {
        const int l = j * 4 + w;
        part[((size_t)(b * 128 + ch) * 64 + l) * 64 + v] = sacc[j];
    }
}

// ---------------------------------------------------------------- reduce partials + squash (+ presence)
__global__ void k_red_squash(const float* __restrict__ part, float* __restrict__ vout,
                             float* __restrict__ pres) {
    const int wv = blockIdx.x;                      // b*64 + l
    const int b = wv >> 6, l = wv & 63;
    const int v = threadIdx.x;
    float acc = 0.f;
    for (int ch = 0; ch < 128; ++ch) acc += part[((size_t)(b * 128 + ch) * 64 + l) * 64 + v];
    float sn = acc * acc;
#pragma unroll
    for (int off = 32; off >= 1; off >>= 1) sn += __shfl_xor(sn, off);
    vout[wv * 64 + v] = acc * sqrtf(sn) / (1.f + sn);
    if (pres != nullptr && v == 0) pres[wv] = sn / (1.f + sn);   // ||squash(s)|| = sn/(1+sn)
}

// ---------------------------------------------------------------- classifier head
__global__ void k_logits(const float* __restrict__ vj, const float* __restrict__ fcw,
                         const float* __restrict__ fcb, float* __restrict__ out) {
    int wv = blockIdx.x * 4 + (threadIdx.x >> 6);   // 0..159
    int lane = threadIdx.x & 63;
    int b = wv / 40, o = wv % 40;
    const float* xv = vj + b * 4096;
    const float* wr = fcw + (size_t)o * 4096;
    float acc = 0.f;
    for (int i = lane; i < 4096; i += 64) acc = fmaf(xv[i], wr[i], acc);
#pragma unroll
    for (int off = 32; off >= 1; off >>= 1) acc += __shfl_xor(acc, off);
    if (lane == 0) out[b * 40 + o] = acc + fcb[o];
}

extern "C" void kernel_launch(void* const* d_in, const int* in_sizes, int n_in,
                              void* d_out, int out_size, void* d_ws, size_t ws_size,
                              hipStream_t stream) {
    const float* x   = (const float*)d_in[0];
    const float* w1  = (const float*)d_in[1];
    // d_in[2] = b1: cancels under batch-norm
    const float* g1  = (const float*)d_in[3];
    const float* be1 = (const float*)d_in[4];
    const float* w2  = (const float*)d_in[5];
    // d_in[6] = b2: cancels
    const float* g2  = (const float*)d_in[7];
    const float* be2 = (const float*)d_in[8];
    const float* w3  = (const float*)d_in[9];
    // d_in[10] = b3: cancels
    const float* g3  = (const float*)d_in[11];
    const float* be3 = (const float*)d_in[12];
    const float* Wr  = (const float*)d_in[13];
    const float* fcw = (const float*)d_in[14];
    const float* fcb = (const float*)d_in[15];
    float* out = (float*)d_out;

    float* ws       = (float*)d_ws;
    float* y1       = ws;                   // [64][8192]
    float* y2       = y1 + 524288;          // [128][8192]
    float* mean1    = y2 + 1048576;         // 64
    float* inv1     = mean1 + 64;           // 64
    float* mean2    = inv1 + 64;            // 128
    float* inv2     = mean2 + 128;          // 128
    float* umax     = inv2 + 128;           // [4][16384] (sign-folded max)
    float* usum_b   = umax + 65536;         // [4][16384] per-b partials (sign-folded)
    float* usumsq_b = usum_b + 65536;       // [4][16384]
    float* u        = usumsq_b + 65536;     // [4][1024][16]
    float* v1       = u + 65536;            // [4][64][64]
    float* v2       = v1 + 16384;
    float* vj       = v2 + 16384;
    float* bij      = vj + 16384;           // [4][64][1024]
    float* s1p      = bij + 262144;         // [32][4][64][64] (2 MB)
    float* part     = s1p + 524288;         // [4][128][64][64] (8 MB)
    float* uhat2    = part + 2097152;       // [4][1024][64][64]  (64 MB), [b][p][l][v]
    // fp16 staging buffers alias the uhat2 region: dead before k_uhat writes it.
    _Float16* w3h = (_Float16*)uhat2;       // [16384][128]
    _Float16* w3l = w3h + 2097152;
    _Float16* h2h = w3l + 2097152;          // [8192][128] (bn-major)
    _Float16* h2l = h2h + 1048576;

    k_conv1stats<<<64, 256, 0, stream>>>(x, w1, y1, mean1, inv1);
    k_conv2<<<dim3(8, 32), 256, 0, stream>>>(y1, w2, mean1, inv1, g1, be1, y2);
    k_stats<<<128, 256, 0, stream>>>(y2, mean2, inv2);
    k_split_w3<<<512, 256, 0, stream>>>(w3, g3, w3h, w3l);
    k_h2t_split<<<dim3(128, 2), 256, 0, stream>>>(y2, mean2, inv2, g2, be2, h2h, h2l);
    // PROBE x4: idempotent replication to surface k_caps in rocprof top-5
    k_caps<<<dim3(128, 4, 4), 256, 0, stream>>>(w3h, w3l, h2h, h2l, umax, usum_b, usumsq_b);
    k_u<<<16, 256, 0, stream>>>(umax, usum_b, usumsq_b, g3, be3, u);
    // PROBE x5: idempotent replication to surface k_uhat in rocprof top-5
    k_uhat<<<dim3(32, 64, 5), 256, 0, stream>>>(Wr, u, uhat2, s1p);
    k_s1red<<<256, 64, 0, stream>>>(s1p, v1);
    // PROBE x8: idempotent replication to surface k_route in rocprof top-5
    k_route<<<dim3(512, 1, 8), 256, 0, stream>>>(uhat2, v1, bij, part, 0);
    k_red_squash<<<256, 64, 0, stream>>>(part, v2, nullptr);
    k_route<<<512, 256, 0, stream>>>(uhat2, v2, bij, part, 1);
    k_red_squash<<<256, 64, 0, stream>>>(part, vj, out + 160);
    k_logits<<<40, 256, 0, stream>>>(vj, fcw, fcb, out);
}

// Round 3
// 725.644 us; speedup vs baseline: 1.8154x; 1.8154x over previous
//
#include <hip/hip_runtime.h>
#include <math.h>

// Dims (fixed by setup_inputs): B=4, N=2048, C1=64, C2=128, P=1024, Q=16, L=64, V=64, OUT=40
// BN = B*N = 8192, QP = Q*P = 16384
#define BN_EPS 1e-5f

typedef __attribute__((ext_vector_type(8))) _Float16 half8;
typedef __attribute__((ext_vector_type(4))) _Float16 half4;
typedef __attribute__((ext_vector_type(4))) float f32x4;
#define SPLIT_S  2048.0f
#define INV_S    (1.0f/2048.0f)

// Round-2 probe results (k_caps x4 surfaced): T_caps=92us (MfmaUtil 53%, Occ 29.6%),
// T_uhat~60-70us (~HBM floor), T_route~10-16us. dur_us is exactly additive ->
// ~450us of the 692 is harness reset work. This round: k_caps occupancy 2->4
// blocks/CU via M-split (bit-identical sums), fuse k_u into k_uhat, fuse
// k_split_w3 into the conv1 dispatch.

// ---------------------------------------------------------------- conv1 + batch stats, fused with w3 split.
// Blocks 0..511: split w3 (fp32 -> fp16 hi + scaled lo, sign(g3) folded).
// Blocks 512..575: conv1 + batch stats (o = bid-512).
__global__ __launch_bounds__(256) void k_pre(const float* __restrict__ x,
        const float* __restrict__ w1, float* __restrict__ y1,
        float* __restrict__ mean, float* __restrict__ inv,
        const float* __restrict__ w3, const float* __restrict__ g3,
        _Float16* __restrict__ hi, _Float16* __restrict__ lo) {
    const int t = threadIdx.x;
    if (blockIdx.x < 512) {
        // ---- split_w3 body (sign of g3 folded: u' = sign(g3)*u so maxpool only needs MAX)
        int base = blockIdx.x * 256 + t;
#pragma unroll
        for (int it = 0; it < 4; ++it) {
            int i = (base + it * 131072) * 4;          // element index
            float4 d = *reinterpret_cast<const float4*>(w3 + i);
            float sgn = (g3[i >> 7] < 0.f) ? -1.f : 1.f;
            float vs[4] = {d.x * sgn, d.y * sgn, d.z * sgn, d.w * sgn};
            half4 h4, l4;
#pragma unroll
            for (int j = 0; j < 4; ++j) {
                _Float16 h = (_Float16)vs[j];
                h4[j] = h;
                l4[j] = (_Float16)((vs[j] - (float)h) * SPLIT_S);
            }
            *reinterpret_cast<half4*>(hi + i) = h4;
            *reinterpret_cast<half4*>(lo + i) = l4;
        }
        return;
    }
    // ---- conv1 + stats body
    const int o = blockIdx.x - 512;
    const float wa = w1[o*3+0], wb = w1[o*3+1], wc = w1[o*3+2];
    float s = 0.f, ss = 0.f;
#pragma unroll
    for (int it = 0; it < 8; ++it) {
        int i = it * 256 + t;                      // 0..2047 : bn/4
        int b = i >> 9, n4 = (i & 511) * 4;
        const float* xb = x + (size_t)b * 6144 + n4;
        float4 x0 = *(const float4*)(xb);
        float4 x1 = *(const float4*)(xb + 2048);
        float4 x2 = *(const float4*)(xb + 4096);
        float4 r;
        r.x = wa*x0.x + wb*x1.x + wc*x2.x;
        r.y = wa*x0.y + wb*x1.y + wc*x2.y;
        r.z = wa*x0.z + wb*x1.z + wc*x2.z;
        r.w = wa*x0.w + wb*x1.w + wc*x2.w;
        *(float4*)(y1 + o * 8192 + i * 4) = r;
        s += r.x + r.y + r.z + r.w;
        ss = fmaf(r.x, r.x, fmaf(r.y, r.y, fmaf(r.z, r.z, fmaf(r.w, r.w, ss))));
    }
    __shared__ float rs[256], rss[256];
    rs[t] = s; rss[t] = ss;
    __syncthreads();
    for (int off = 128; off > 0; off >>= 1) {
        if (t < off) { rs[t] += rs[t+off]; rss[t] += rss[t+off]; }
        __syncthreads();
    }
    if (t == 0) {
        float m = rs[0] * (1.f/8192.f);
        float var = rss[0] * (1.f/8192.f) - m*m;
        mean[o] = m;
        inv[o]  = rsqrtf(var + BN_EPS);
    }
}

// ---------------------------------------------------------------- per-channel batch stats (for y2)
__global__ void k_stats(const float* __restrict__ y, float* __restrict__ mean,
                        float* __restrict__ inv) {
    int c = blockIdx.x, t = threadIdx.x;
    float s = 0.f, ss = 0.f;
    const float4* src = (const float4*)(y + c * 8192);
    for (int i = t; i < 2048; i += 256) {
        float4 v = src[i];
        s += v.x + v.y + v.z + v.w;
        ss = fmaf(v.x, v.x, fmaf(v.y, v.y, fmaf(v.z, v.z, fmaf(v.w, v.w, ss))));
    }
    __shared__ float rs[256], rss[256];
    rs[t] = s; rss[t] = ss;
    __syncthreads();
    for (int off = 128; off > 0; off >>= 1) {
        if (t < off) { rs[t] += rs[t+off]; rss[t] += rss[t+off]; }
        __syncthreads();
    }
    if (t == 0) {
        float m = rs[0] * (1.f/8192.f);
        float var = rss[0] * (1.f/8192.f) - m*m;
        mean[c] = m;
        inv[c]  = rsqrtf(var + BN_EPS);
    }
}

// ---------------------------------------------------------------- conv2 with BN1+ReLU fused on load
__global__ __launch_bounds__(256) void k_conv2(const float* __restrict__ y1,
        const float* __restrict__ w2,
        const float* __restrict__ mean1, const float* __restrict__ inv1,
        const float* __restrict__ g1, const float* __restrict__ be1,
        float* __restrict__ y2) {
    __shared__ float sc1[64], sh1[64];
    const int t = threadIdx.x;
    if (t < 64) {
        float sc = inv1[t] * g1[t];
        sc1[t] = sc;
        sh1[t] = be1[t] - mean1[t] * sc;
    }
    __syncthreads();
    int bn0 = (blockIdx.x * 256 + t) * 4;
    int og0 = blockIdx.y * 4;
    float4 acc[4];
#pragma unroll
    for (int j = 0; j < 4; ++j) acc[j] = float4{0.f,0.f,0.f,0.f};
    for (int c = 0; c < 64; ++c) {
        float4 hv = *(const float4*)(y1 + c*8192 + bn0);
        float sc = sc1[c], sh = sh1[c];
        hv.x = fmaxf(fmaf(hv.x, sc, sh), 0.f);
        hv.y = fmaxf(fmaf(hv.y, sc, sh), 0.f);
        hv.z = fmaxf(fmaf(hv.z, sc, sh), 0.f);
        hv.w = fmaxf(fmaf(hv.w, sc, sh), 0.f);
#pragma unroll
        for (int j = 0; j < 4; ++j) {
            float w = w2[(og0+j)*64 + c];
            acc[j].x = fmaf(w, hv.x, acc[j].x); acc[j].y = fmaf(w, hv.y, acc[j].y);
            acc[j].z = fmaf(w, hv.z, acc[j].z); acc[j].w = fmaf(w, hv.w, acc[j].w);
        }
    }
#pragma unroll
    for (int j = 0; j < 4; ++j) *(float4*)(y2 + (og0+j)*8192 + bn0) = acc[j];
}

// ---------------------------------------------------------------- BN2+ReLU fused with transpose+split
__global__ __launch_bounds__(256) void k_h2t_split(const float* __restrict__ y2,
        const float* __restrict__ mean, const float* __restrict__ inv,
        const float* __restrict__ g, const float* __restrict__ be,
        _Float16* __restrict__ hi, _Float16* __restrict__ lo) {
    __shared__ float tile[64][65];
    const int t = threadIdx.x;
    const int bn0 = blockIdx.x * 64, c0 = blockIdx.y * 64;
#pragma unroll
    for (int r = 0; r < 4; ++r) {
        int idx = r * 256 + t;                     // 0..1023, 4 elems each
        int cl = idx >> 4, bn4 = (idx & 15) * 4;
        int c = c0 + cl;
        float sc = inv[c] * g[c];
        float sh = be[c] - mean[c] * sc;
        float4 d = *(const float4*)(y2 + (size_t)c * 8192 + bn0 + bn4);
        tile[cl][bn4  ] = fmaxf(fmaf(d.x, sc, sh), 0.f);
        tile[cl][bn4+1] = fmaxf(fmaf(d.y, sc, sh), 0.f);
        tile[cl][bn4+2] = fmaxf(fmaf(d.z, sc, sh), 0.f);
        tile[cl][bn4+3] = fmaxf(fmaf(d.w, sc, sh), 0.f);
    }
    __syncthreads();
#pragma unroll
    for (int r = 0; r < 4; ++r) {
        int idx = r * 256 + t;
        int bnl = idx >> 4, c4 = (idx & 15) * 4;
        half4 h4, l4;
#pragma unroll
        for (int j = 0; j < 4; ++j) {
            float v = tile[c4 + j][bnl];
            _Float16 h = (_Float16)v;
            h4[j] = h;
            l4[j] = (_Float16)((v - (float)h) * SPLIT_S);
        }
        size_t o = (size_t)(bn0 + bnl) * 128 + c0 + c4;
        *reinterpret_cast<half4*>(hi + o) = h4;
        *reinterpret_cast<half4*>(lo + o) = l4;
    }
}

// ---------------------------------------------------------------- THE BIG ONE v7.
// u'[qp][bn] = (sign-folded w3)[qp][:].h2[:][bn], K=128, fp16x3 split MFMA.
// M-split vs v6: each wave owns 16 rows (not 32); grid x doubled to 256 ->
// 1024 blocks = 4 blocks/CU (was 2). Stats summation order is bit-identical
// (per-row accumulation still nt=0..63, g inner, within one wave).
__global__ __launch_bounds__(256, 4) void k_caps(
        const _Float16* __restrict__ w3h, const _Float16* __restrict__ w3l,
        const _Float16* __restrict__ h2h, const _Float16* __restrict__ h2l,
        float* __restrict__ umax,
        float* __restrict__ usum_b, float* __restrict__ usumsq_b) {
    const int lane = threadIdx.x & 63, wave = threadIdx.x >> 6;
    const int b = blockIdx.y;
    const int mrow = blockIdx.x * 64 + wave * 16;
    const int r16 = lane & 15, kq = lane >> 4;     // frag: row/col=lane&15, k=kq*8+j

    __shared__ _Float16 Bs[2][2][8][64][8];        // [buf][g][ks*2+h][lane][j] 32 KB

    half8 Ah[4], Al[4];
    const size_t abase = (size_t)(mrow + r16) * 128 + kq * 8;
#pragma unroll
    for (int ks = 0; ks < 4; ++ks) {
        Ah[ks] = *reinterpret_cast<const half8*>(w3h + abase + ks*32);
        Al[ks] = *reinterpret_cast<const half8*>(w3l + abase + ks*32);
    }
    float mx[4], sm[4], sq[4];
#pragma unroll
    for (int r = 0; r < 4; ++r) { mx[r] = -3.4e38f; sm[r] = 0.f; sq[r] = 0.f; }

    // staging: thread covers units u0=wave*2 (h2h) and u0+1 (h2l), k-off = wave*32+kq*8
    const int u0 = wave * 2;
    const size_t srow = (size_t)(b*2048 + r16) * 128 + wave * 32 + kq * 8;

    { // prologue: stage nt=0 (cols 0..31) into buf 0
#pragma unroll
        for (int g = 0; g < 2; ++g) {
            const size_t a = srow + (size_t)g * 16 * 128;
            *reinterpret_cast<half8*>(&Bs[0][g][u0  ][lane][0]) = *reinterpret_cast<const half8*>(h2h + a);
            *reinterpret_cast<half8*>(&Bs[0][g][u0+1][lane][0]) = *reinterpret_cast<const half8*>(h2l + a);
        }
    }
    __syncthreads();

    for (int nt = 0; nt < 64; ++nt) {              // 32 cols per iter
        const int buf = nt & 1;
        const int ntn = (nt + 1 < 64) ? nt + 1 : nt;
        const size_t snext = srow + (size_t)ntn * 32 * 128;
        half8 g0h = *reinterpret_cast<const half8*>(h2h + snext);
        half8 g0l = *reinterpret_cast<const half8*>(h2l + snext);
        half8 g1h = *reinterpret_cast<const half8*>(h2h + snext + 2048);
        half8 g1l = *reinterpret_cast<const half8*>(h2l + snext + 2048);

#pragma unroll
        for (int g = 0; g < 2; ++g) {
            f32x4 acc = f32x4{0.f,0.f,0.f,0.f};
            f32x4 accx = f32x4{0.f,0.f,0.f,0.f};
#pragma unroll
            for (int ks = 0; ks < 4; ++ks) {
                half8 Bh = *reinterpret_cast<const half8*>(&Bs[buf][g][ks*2  ][lane][0]);
                half8 Bl = *reinterpret_cast<const half8*>(&Bs[buf][g][ks*2+1][lane][0]);
                acc  = __builtin_amdgcn_mfma_f32_16x16x32_f16(Ah[ks], Bh, acc, 0, 0, 0);
                accx = __builtin_amdgcn_mfma_f32_16x16x32_f16(Ah[ks], Bl, accx, 0, 0, 0);
                accx = __builtin_amdgcn_mfma_f32_16x16x32_f16(Al[ks], Bh, accx, 0, 0, 0);
            }
#pragma unroll
            for (int r = 0; r < 4; ++r) {
                float v = fmaf(accx[r], INV_S, acc[r]);
                mx[r] = fmaxf(mx[r], v);
                sm[r] += v;
                sq[r] = fmaf(v, v, sq[r]);
            }
        }
        *reinterpret_cast<half8*>(&Bs[buf^1][0][u0  ][lane][0]) = g0h;
        *reinterpret_cast<half8*>(&Bs[buf^1][0][u0+1][lane][0]) = g0l;
        *reinterpret_cast<half8*>(&Bs[buf^1][1][u0  ][lane][0]) = g1h;
        *reinterpret_cast<half8*>(&Bs[buf^1][1][u0+1][lane][0]) = g1l;
        __syncthreads();
    }

    // reduce over the 16 column lanes (C/D: col=lane&15, row=kq*4+reg)
#pragma unroll
    for (int off = 8; off >= 1; off >>= 1)
#pragma unroll
        for (int r = 0; r < 4; ++r) {
            mx[r] = fmaxf(mx[r], __shfl_xor(mx[r], off));
            sm[r] += __shfl_xor(sm[r], off);
            sq[r] += __shfl_xor(sq[r], off);
        }
    if (r16 == 0) {
#pragma unroll
        for (int r = 0; r < 4; ++r) {
            int qp = mrow + kq*4 + r;
            umax[b*16384 + qp]     = mx[r];
            usum_b[b*16384 + qp]   = sm[r];
            usumsq_b[b*16384 + qp] = sq[r];
        }
    }
}

// ---------------------------------------------------------------- u_hat + fused BN3/squash (k_u absorbed) + p-partial sums.
__global__ __launch_bounds__(256) void k_uhat(const float* __restrict__ Wr,
                                              const float* __restrict__ umax,
                                              const float* __restrict__ usum_b,
                                              const float* __restrict__ usumsq_b,
                                              const float* __restrict__ g3,
                                              const float* __restrict__ be3,
                                              float* __restrict__ uhat2,
                                              float* __restrict__ s1p) {
    const int t = threadIdx.x;
    const int pblk = blockIdx.x, l = blockIdx.y;
    __shared__ float wr[4][64][20];                // [p][v][q] q-contiguous, padded
    __shared__ float us_all[32][4][16];            // [p][b][q] for this block's 32 p
    const int bb = t >> 6, v = t & 63;

    // compute this block's u slice (BN3 analytic sign-folded + squash), bit-identical to old k_u
    if (t < 128) {
        int p = t & 31, b2 = t >> 5;
        int pg = pblk * 32 + p;
        float ub[16]; float sn = 0.f;
#pragma unroll
        for (int q = 0; q < 16; ++q) {
            int qp = q * 1024 + pg;
            float s  = usum_b[qp] + usum_b[16384+qp] + usum_b[32768+qp] + usum_b[49152+qp];
            float ss = usumsq_b[qp] + usumsq_b[16384+qp] + usumsq_b[32768+qp] + usumsq_b[49152+qp];
            float g  = g3[qp];
            float sgn = (g < 0.f) ? -1.f : 1.f;
            float mean  = sgn * s * (1.f/8192.f);
            float var   = ss * (1.f/8192.f) - mean*mean;
            float scale = g * rsqrtf(var + BN_EPS);
            float val = sgn * umax[b2*16384 + qp];
            float vb = (val - mean) * scale + be3[qp];
            ub[q] = vb; sn = fmaf(vb, vb, sn);
        }
        float f = sqrtf(sn) / (1.f + sn);
#pragma unroll
        for (int q = 0; q < 16; ++q) us_all[p][b2][q] = ub[q] * f;
    }

    float s1acc = 0.f;
    for (int sub = 0; sub < 8; ++sub) {
        const int p0 = pblk * 32 + sub * 4;
        const float* src = Wr + ((size_t)l * 1024 + p0) * 1024;
        if (sub) __syncthreads();                  // LDS reuse guard
#pragma unroll
        for (int it = 0; it < 4; ++it) {
            float4 d = *(const float4*)(src + (it*256 + t) * 4);
            int vv = t >> 2, q0 = (t & 3) * 4;     // p = it
            *(float4*)&wr[it][vv][q0] = d;
        }
        __syncthreads();                           // also orders us_all init (sub==0)
#pragma unroll
        for (int p = 0; p < 4; ++p) {
            float acc = 0.f;
            const int pl = sub * 4 + p;
#pragma unroll
            for (int q4 = 0; q4 < 4; ++q4) {
                float4 wf = *(const float4*)&wr[p][v][q4*4];
                float4 uf = *(const float4*)&us_all[pl][bb][q4*4];
                acc = fmaf(wf.x, uf.x, acc);
                acc = fmaf(wf.y, uf.y, acc);
                acc = fmaf(wf.z, uf.z, acc);
                acc = fmaf(wf.w, uf.w, acc);
            }
            uhat2[(((size_t)bb * 1024 + p0 + p) * 64 + l) * 64 + v] = acc;
            s1acc += acc;
        }
    }
    s1p[(((size_t)pblk * 4 + bb) * 64 + l) * 64 + v] = s1acc;
}

// ---------------------------------------------------------------- reduce s1 partials + squash -> v1
__global__ void k_s1red(const float* __restrict__ s1p, float* __restrict__ vout) {
    const int wv = blockIdx.x;                      // b*64 + l
    const int b = wv >> 6, l = wv & 63;
    const int v = threadIdx.x;
    float acc = 0.f;
#pragma unroll
    for (int pblk = 0; pblk < 32; ++pblk)
        acc += s1p[(((size_t)pblk * 4 + b) * 64 + l) * 64 + v];
    float s = acc * (1.f/64.f);
    float sn = s * s;
#pragma unroll
    for (int off = 32; off >= 1; off >>= 1) sn += __shfl_xor(sn, off);
    vout[wv * 64 + v] = s * sqrtf(sn) / (1.f + sn);
}

// ---------------------------------------------------------------- routing pass (B or C).
__global__ __launch_bounds__(256) void k_route(const float* __restrict__ uhat2,
                                               const float* __restrict__ vin,
                                               float* __restrict__ bij,
                                               float* __restrict__ part, const int read_b) {
    const int blk = blockIdx.x;
    const int b = blk >> 7, ch = blk & 127;
    const int p0 = ch * 8;
    const int t = threadIdx.x;
    const int v = t & 63, w = t >> 6;
    __shared__ float uh[64][68];
    __shared__ float vs[64][68];
    __shared__ float bl[64];
    {
        const float* src = vin + b * 4096;
        for (int i = t; i < 1024; i += 256) {
            float4 d = *(const float4*)(src + i * 4);
            int l = i >> 4, v0 = (i & 15) * 4;
            vs[l][v0] = d.x; vs[l][v0+1] = d.y; vs[l][v0+2] = d.z; vs[l][v0+3] = d.w;
        }
    }
    float sacc[16];
#pragma unroll
    for (int j = 0; j < 16; ++j) sacc[j] = 0.f;

    for (int pp = 0; pp < 8; ++pp) {
        const int p = p0 + pp;
        __syncthreads();                            // uh/bl reuse guard (covers vs on pp=0)
        const float* src = uhat2 + ((size_t)b * 1024 + p) * 4096;   // contiguous 16 KB
        for (int i = t; i < 1024; i += 256) {
            float4 d = *(const float4*)(src + i * 4);
            int l = i >> 4, v0 = (i & 15) * 4;
            uh[l][v0] = d.x; uh[l][v0+1] = d.y; uh[l][v0+2] = d.z; uh[l][v0+3] = d.w;
        }
        __syncthreads();
#pragma unroll
        for (int i = 0; i < 16; ++i) {
            const int l = w * 16 + i;
            float prod = uh[l][v] * vs[l][v];
#pragma unroll
            for (int off = 32; off >= 1; off >>= 1) prod += __shfl_xor(prod, off);
            if (v == 0) {
                float bb = prod;
                if (read_b) bb += bij[(b * 64 + l) * 1024 + p];
                bl[l] = bb;
                if (!read_b) bij[(b * 64 + l) * 1024 + p] = bb;
            }
        }
        __syncthreads();
        // all-wave softmax over l, in registers: lane v holds x[l=v]
        float xv = bl[v];
        float m = xv;
#pragma unroll
        for (int off = 32; off >= 1; off >>= 1) m = fmaxf(m, __shfl_xor(m, off));
        float e = expf(xv - m);
        float sgm = e;
#pragma unroll
        for (int off = 32; off >= 1; off >>= 1) sgm += __shfl_xor(sgm, off);
        float c = e / sgm;                          // c[l=v]
#pragma unroll
        for (int j = 0; j < 16; ++j) {
            const int l = j * 4 + w;
            float cl = __shfl(c, l);
            sacc[j] = fmaf(cl, uh[l][v], sacc[j]);
        }
    }
#pragma unroll
    for (int j = 0; j < 16; ++j) {
        const int l = j * 4 + w;
        part[((size_t)(b * 128 + ch) * 64 + l) * 64 + v] = sacc[j];
    }
}

// ---------------------------------------------------------------- reduce partials + squash (+ presence)
__global__ void k_red_squash(const float* __restrict__ part, float* __restrict__ vout,
                             float* __restrict__ pres) {
    const int wv = blockIdx.x;                      // b*64 + l
    const int b = wv >> 6, l = wv & 63;
    const int v = threadIdx.x;
    float acc = 0.f;
    for (int ch = 0; ch < 128; ++ch) acc += part[((size_t)(b * 128 + ch) * 64 + l) * 64 + v];
    float sn = acc * acc;
#pragma unroll
    for (int off = 32; off >= 1; off >>= 1) sn += __shfl_xor(sn, off);
    vout[wv * 64 + v] = acc * sqrtf(sn) / (1.f + sn);
    if (pres != nullptr && v == 0) pres[wv] = sn / (1.f + sn);   // ||squash(s)|| = sn/(1+sn)
}

// ---------------------------------------------------------------- classifier head
__global__ void k_logits(const float* __restrict__ vj, const float* __restrict__ fcw,
                         const float* __restrict__ fcb, float* __restrict__ out) {
    int wv = blockIdx.x * 4 + (threadIdx.x >> 6);   // 0..159
    int lane = threadIdx.x & 63;
    int b = wv / 40, o = wv % 40;
    const float* xv = vj + b * 4096;
    const float* wr = fcw + (size_t)o * 4096;
    float acc = 0.f;
    for (int i = lane; i < 4096; i += 64) acc = fmaf(xv[i], wr[i], acc);
#pragma unroll
    for (int off = 32; off >= 1; off >>= 1) acc += __shfl_xor(acc, off);
    if (lane == 0) out[b * 40 + o] = acc + fcb[o];
}

extern "C" void kernel_launch(void* const* d_in, const int* in_sizes, int n_in,
                              void* d_out, int out_size, void* d_ws, size_t ws_size,
                              hipStream_t stream) {
    const float* x   = (const float*)d_in[0];
    const float* w1  = (const float*)d_in[1];
    // d_in[2] = b1: cancels under batch-norm
    const float* g1  = (const float*)d_in[3];
    const float* be1 = (const float*)d_in[4];
    const float* w2  = (const float*)d_in[5];
    // d_in[6] = b2: cancels
    const float* g2  = (const float*)d_in[7];
    const float* be2 = (const float*)d_in[8];
    const float* w3  = (const float*)d_in[9];
    // d_in[10] = b3: cancels
    const float* g3  = (const float*)d_in[11];
    const float* be3 = (const float*)d_in[12];
    const float* Wr  = (const float*)d_in[13];
    const float* fcw = (const float*)d_in[14];
    const float* fcb = (const float*)d_in[15];
    float* out = (float*)d_out;

    float* ws       = (float*)d_ws;
    float* y1       = ws;                   // [64][8192]
    float* y2       = y1 + 524288;          // [128][8192]
    float* mean1    = y2 + 1048576;         // 64
    float* inv1     = mean1 + 64;           // 64
    float* mean2    = inv1 + 64;            // 128
    float* inv2     = mean2 + 128;          // 128
    float* umax     = inv2 + 128;           // [4][16384] (sign-folded max)
    float* usum_b   = umax + 65536;         // [4][16384] per-b partials (sign-folded)
    float* usumsq_b = usum_b + 65536;       // [4][16384]
    float* u_unused = usumsq_b + 65536;     // (dead; kept for layout stability)
    float* v1       = u_unused + 65536;     // [4][64][64]
    float* v2       = v1 + 16384;
    float* vj       = v2 + 16384;
    float* bij      = vj + 16384;           // [4][64][1024]
    float* s1p      = bij + 262144;         // [32][4][64][64] (2 MB)
    float* part     = s1p + 524288;         // [4][128][64][64] (8 MB)
    float* uhat2    = part + 2097152;       // [4][1024][64][64]  (64 MB), [b][p][l][v]
    // fp16 staging buffers alias the uhat2 region: dead before k_uhat writes it.
    _Float16* w3h = (_Float16*)uhat2;       // [16384][128]
    _Float16* w3l = w3h + 2097152;
    _Float16* h2h = w3l + 2097152;          // [8192][128] (bn-major)
    _Float16* h2l = h2h + 1048576;

    k_pre<<<576, 256, 0, stream>>>(x, w1, y1, mean1, inv1, w3, g3, w3h, w3l);
    k_conv2<<<dim3(8, 32), 256, 0, stream>>>(y1, w2, mean1, inv1, g1, be1, y2);
    k_stats<<<128, 256, 0, stream>>>(y2, mean2, inv2);
    k_h2t_split<<<dim3(128, 2), 256, 0, stream>>>(y2, mean2, inv2, g2, be2, h2h, h2l);
    k_caps<<<dim3(256, 4), 256, 0, stream>>>(w3h, w3l, h2h, h2l, umax, usum_b, usumsq_b);
    k_uhat<<<dim3(32, 64), 256, 0, stream>>>(Wr, umax, usum_b, usumsq_b, g3, be3, uhat2, s1p);
    k_s1red<<<256, 64, 0, stream>>>(s1p, v1);
    k_route<<<512, 256, 0, stream>>>(uhat2, v1, bij, part, 0);
    k_red_squash<<<256, 64, 0, stream>>>(part, v2, nullptr);
    k_route<<<512, 256, 0, stream>>>(uhat2, v2, bij, part, 1);
    k_red_squash<<<256, 64, 0, stream>>>(part, vj, out + 160);
    k_logits<<<40, 256, 0, stream>>>(vj, fcw, fcb, out);
}

// Round 4
// 686.258 us; speedup vs baseline: 1.9196x; 1.0574x over previous
//
#include <hip/hip_runtime.h>
#include <math.h>

// Dims (fixed by setup_inputs): B=4, N=2048, C1=64, C2=128, P=1024, Q=16, L=64, V=64, OUT=40
// BN = B*N = 8192, QP = Q*P = 16384
#define BN_EPS 1e-5f

typedef __attribute__((ext_vector_type(8))) _Float16 half8;
typedef __attribute__((ext_vector_type(4))) _Float16 half4;
typedef __attribute__((ext_vector_type(4))) float f32x4;
#define SPLIT_S  2048.0f
#define INV_S    (1.0f/2048.0f)

// Cost model (round-2 probe): kernels ~240us of dur_us; ~450us is harness reset.
// T_caps=92 (v6 schedule), T_uhat~65 (~HBM floor 51), T_route~12 each.
// Round-3 M-split REGRESSED (+33): blocks x staging doubled at constant MFMA.
// This round: k_caps restored to exact v6; keep k_pre + fused k_uhat (isolate sign).

// ---------------------------------------------------------------- conv1 + batch stats, fused with w3 split.
// Blocks 0..511: split w3 (fp32 -> fp16 hi + scaled lo, sign(g3) folded).
// Blocks 512..575: conv1 + batch stats (o = bid-512).
__global__ __launch_bounds__(256) void k_pre(const float* __restrict__ x,
        const float* __restrict__ w1, float* __restrict__ y1,
        float* __restrict__ mean, float* __restrict__ inv,
        const float* __restrict__ w3, const float* __restrict__ g3,
        _Float16* __restrict__ hi, _Float16* __restrict__ lo) {
    const int t = threadIdx.x;
    if (blockIdx.x < 512) {
        // ---- split_w3 body (sign of g3 folded: u' = sign(g3)*u so maxpool only needs MAX)
        int base = blockIdx.x * 256 + t;
#pragma unroll
        for (int it = 0; it < 4; ++it) {
            int i = (base + it * 131072) * 4;          // element index
            float4 d = *reinterpret_cast<const float4*>(w3 + i);
            float sgn = (g3[i >> 7] < 0.f) ? -1.f : 1.f;
            float vs[4] = {d.x * sgn, d.y * sgn, d.z * sgn, d.w * sgn};
            half4 h4, l4;
#pragma unroll
            for (int j = 0; j < 4; ++j) {
                _Float16 h = (_Float16)vs[j];
                h4[j] = h;
                l4[j] = (_Float16)((vs[j] - (float)h) * SPLIT_S);
            }
            *reinterpret_cast<half4*>(hi + i) = h4;
            *reinterpret_cast<half4*>(lo + i) = l4;
        }
        return;
    }
    // ---- conv1 + stats body
    const int o = blockIdx.x - 512;
    const float wa = w1[o*3+0], wb = w1[o*3+1], wc = w1[o*3+2];
    float s = 0.f, ss = 0.f;
#pragma unroll
    for (int it = 0; it < 8; ++it) {
        int i = it * 256 + t;                      // 0..2047 : bn/4
        int b = i >> 9, n4 = (i & 511) * 4;
        const float* xb = x + (size_t)b * 6144 + n4;
        float4 x0 = *(const float4*)(xb);
        float4 x1 = *(const float4*)(xb + 2048);
        float4 x2 = *(const float4*)(xb + 4096);
        float4 r;
        r.x = wa*x0.x + wb*x1.x + wc*x2.x;
        r.y = wa*x0.y + wb*x1.y + wc*x2.y;
        r.z = wa*x0.z + wb*x1.z + wc*x2.z;
        r.w = wa*x0.w + wb*x1.w + wc*x2.w;
        *(float4*)(y1 + o * 8192 + i * 4) = r;
        s += r.x + r.y + r.z + r.w;
        ss = fmaf(r.x, r.x, fmaf(r.y, r.y, fmaf(r.z, r.z, fmaf(r.w, r.w, ss))));
    }
    __shared__ float rs[256], rss[256];
    rs[t] = s; rss[t] = ss;
    __syncthreads();
    for (int off = 128; off > 0; off >>= 1) {
        if (t < off) { rs[t] += rs[t+off]; rss[t] += rss[t+off]; }
        __syncthreads();
    }
    if (t == 0) {
        float m = rs[0] * (1.f/8192.f);
        float var = rss[0] * (1.f/8192.f) - m*m;
        mean[o] = m;
        inv[o]  = rsqrtf(var + BN_EPS);
    }
}

// ---------------------------------------------------------------- per-channel batch stats (for y2)
__global__ void k_stats(const float* __restrict__ y, float* __restrict__ mean,
                        float* __restrict__ inv) {
    int c = blockIdx.x, t = threadIdx.x;
    float s = 0.f, ss = 0.f;
    const float4* src = (const float4*)(y + c * 8192);
    for (int i = t; i < 2048; i += 256) {
        float4 v = src[i];
        s += v.x + v.y + v.z + v.w;
        ss = fmaf(v.x, v.x, fmaf(v.y, v.y, fmaf(v.z, v.z, fmaf(v.w, v.w, ss))));
    }
    __shared__ float rs[256], rss[256];
    rs[t] = s; rss[t] = ss;
    __syncthreads();
    for (int off = 128; off > 0; off >>= 1) {
        if (t < off) { rs[t] += rs[t+off]; rss[t] += rss[t+off]; }
        __syncthreads();
    }
    if (t == 0) {
        float m = rs[0] * (1.f/8192.f);
        float var = rss[0] * (1.f/8192.f) - m*m;
        mean[c] = m;
        inv[c]  = rsqrtf(var + BN_EPS);
    }
}

// ---------------------------------------------------------------- conv2 with BN1+ReLU fused on load
__global__ __launch_bounds__(256) void k_conv2(const float* __restrict__ y1,
        const float* __restrict__ w2,
        const float* __restrict__ mean1, const float* __restrict__ inv1,
        const float* __restrict__ g1, const float* __restrict__ be1,
        float* __restrict__ y2) {
    __shared__ float sc1[64], sh1[64];
    const int t = threadIdx.x;
    if (t < 64) {
        float sc = inv1[t] * g1[t];
        sc1[t] = sc;
        sh1[t] = be1[t] - mean1[t] * sc;
    }
    __syncthreads();
    int bn0 = (blockIdx.x * 256 + t) * 4;
    int og0 = blockIdx.y * 4;
    float4 acc[4];
#pragma unroll
    for (int j = 0; j < 4; ++j) acc[j] = float4{0.f,0.f,0.f,0.f};
    for (int c = 0; c < 64; ++c) {
        float4 hv = *(const float4*)(y1 + c*8192 + bn0);
        float sc = sc1[c], sh = sh1[c];
        hv.x = fmaxf(fmaf(hv.x, sc, sh), 0.f);
        hv.y = fmaxf(fmaf(hv.y, sc, sh), 0.f);
        hv.z = fmaxf(fmaf(hv.z, sc, sh), 0.f);
        hv.w = fmaxf(fmaf(hv.w, sc, sh), 0.f);
#pragma unroll
        for (int j = 0; j < 4; ++j) {
            float w = w2[(og0+j)*64 + c];
            acc[j].x = fmaf(w, hv.x, acc[j].x); acc[j].y = fmaf(w, hv.y, acc[j].y);
            acc[j].z = fmaf(w, hv.z, acc[j].z); acc[j].w = fmaf(w, hv.w, acc[j].w);
        }
    }
#pragma unroll
    for (int j = 0; j < 4; ++j) *(float4*)(y2 + (og0+j)*8192 + bn0) = acc[j];
}

// ---------------------------------------------------------------- BN2+ReLU fused with transpose+split
__global__ __launch_bounds__(256) void k_h2t_split(const float* __restrict__ y2,
        const float* __restrict__ mean, const float* __restrict__ inv,
        const float* __restrict__ g, const float* __restrict__ be,
        _Float16* __restrict__ hi, _Float16* __restrict__ lo) {
    __shared__ float tile[64][65];
    const int t = threadIdx.x;
    const int bn0 = blockIdx.x * 64, c0 = blockIdx.y * 64;
#pragma unroll
    for (int r = 0; r < 4; ++r) {
        int idx = r * 256 + t;                     // 0..1023, 4 elems each
        int cl = idx >> 4, bn4 = (idx & 15) * 4;
        int c = c0 + cl;
        float sc = inv[c] * g[c];
        float sh = be[c] - mean[c] * sc;
        float4 d = *(const float4*)(y2 + (size_t)c * 8192 + bn0 + bn4);
        tile[cl][bn4  ] = fmaxf(fmaf(d.x, sc, sh), 0.f);
        tile[cl][bn4+1] = fmaxf(fmaf(d.y, sc, sh), 0.f);
        tile[cl][bn4+2] = fmaxf(fmaf(d.z, sc, sh), 0.f);
        tile[cl][bn4+3] = fmaxf(fmaf(d.w, sc, sh), 0.f);
    }
    __syncthreads();
#pragma unroll
    for (int r = 0; r < 4; ++r) {
        int idx = r * 256 + t;
        int bnl = idx >> 4, c4 = (idx & 15) * 4;
        half4 h4, l4;
#pragma unroll
        for (int j = 0; j < 4; ++j) {
            float v = tile[c4 + j][bnl];
            _Float16 h = (_Float16)v;
            h4[j] = h;
            l4[j] = (_Float16)((v - (float)h) * SPLIT_S);
        }
        size_t o = (size_t)(bn0 + bnl) * 128 + c0 + c4;
        *reinterpret_cast<half4*>(hi + o) = h4;
        *reinterpret_cast<half4*>(lo + o) = l4;
    }
}

// ---------------------------------------------------------------- THE BIG ONE v6 (restored; proven 92us).
// u'[qp][bn] = (sign-folded w3)[qp][:].h2[:][bn], K=128, fp16x3 split MFMA.
// 4 waves split M (2 m-tiles each, A in regs). 32-col B tiles (2 groups of
// 16) staged in LDS in fragment order, double-buffered: 64 barriers, 48
// MFMA per barrier. Stats (per-b max, sum/sq) fused in epilogue.
// NOTE (round-3 lesson): cost ~ blocks x (staging+barriers); do NOT split M
// into more blocks at constant B coverage.
__global__ __launch_bounds__(256, 2) void k_caps(
        const _Float16* __restrict__ w3h, const _Float16* __restrict__ w3l,
        const _Float16* __restrict__ h2h, const _Float16* __restrict__ h2l,
        float* __restrict__ umax,
        float* __restrict__ usum_b, float* __restrict__ usumsq_b) {
    const int lane = threadIdx.x & 63, wave = threadIdx.x >> 6;
    const int b = blockIdx.y;
    const int mrow = blockIdx.x * 128 + wave * 32;
    const int r16 = lane & 15, kq = lane >> 4;     // frag: row/col=lane&15, k=kq*8+j

    __shared__ _Float16 Bs[2][2][8][64][8];        // [buf][g][ks*2+h][lane][j] 32 KB

    half8 Ah[2][4], Al[2][4];
#pragma unroll
    for (int mt = 0; mt < 2; ++mt) {
        const size_t base = (size_t)(mrow + mt*16 + r16) * 128 + kq * 8;
#pragma unroll
        for (int ks = 0; ks < 4; ++ks) {
            Ah[mt][ks] = *reinterpret_cast<const half8*>(w3h + base + ks*32);
            Al[mt][ks] = *reinterpret_cast<const half8*>(w3l + base + ks*32);
        }
    }
    float mx[2][4], sm[2][4], sq[2][4];
#pragma unroll
    for (int mt = 0; mt < 2; ++mt)
#pragma unroll
        for (int r = 0; r < 4; ++r) {
            mx[mt][r] = -3.4e38f; sm[mt][r] = 0.f; sq[mt][r] = 0.f;
        }

    const int u0 = wave * 2;
    const size_t srow = (size_t)(b*2048 + r16) * 128 + wave * 32 + kq * 8;

    { // prologue: stage nt=0 into buf 0
#pragma unroll
        for (int g = 0; g < 2; ++g) {
            const size_t a = srow + (size_t)g * 16 * 128;
            *reinterpret_cast<half8*>(&Bs[0][g][u0  ][lane][0]) = *reinterpret_cast<const half8*>(h2h + a);
            *reinterpret_cast<half8*>(&Bs[0][g][u0+1][lane][0]) = *reinterpret_cast<const half8*>(h2l + a);
        }
    }
    __syncthreads();

    for (int nt = 0; nt < 64; ++nt) {              // 32 cols per iter
        const int buf = nt & 1;
        const int ntn = (nt + 1 < 64) ? nt + 1 : nt;
        const size_t snext = srow + (size_t)ntn * 32 * 128;
        half8 g0h = *reinterpret_cast<const half8*>(h2h + snext);
        half8 g0l = *reinterpret_cast<const half8*>(h2l + snext);
        half8 g1h = *reinterpret_cast<const half8*>(h2h + snext + 2048);
        half8 g1l = *reinterpret_cast<const half8*>(h2l + snext + 2048);

#pragma unroll
        for (int g = 0; g < 2; ++g) {
            f32x4 acc[2], accx[2];
#pragma unroll
            for (int mt = 0; mt < 2; ++mt) { acc[mt] = f32x4{0.f,0.f,0.f,0.f}; accx[mt] = f32x4{0.f,0.f,0.f,0.f}; }
#pragma unroll
            for (int ks = 0; ks < 4; ++ks) {
                half8 Bh = *reinterpret_cast<const half8*>(&Bs[buf][g][ks*2  ][lane][0]);
                half8 Bl = *reinterpret_cast<const half8*>(&Bs[buf][g][ks*2+1][lane][0]);
#pragma unroll
                for (int mt = 0; mt < 2; ++mt) {
                    acc[mt]  = __builtin_amdgcn_mfma_f32_16x16x32_f16(Ah[mt][ks], Bh, acc[mt], 0, 0, 0);
                    accx[mt] = __builtin_amdgcn_mfma_f32_16x16x32_f16(Ah[mt][ks], Bl, accx[mt], 0, 0, 0);
                    accx[mt] = __builtin_amdgcn_mfma_f32_16x16x32_f16(Al[mt][ks], Bh, accx[mt], 0, 0, 0);
                }
            }
#pragma unroll
            for (int mt = 0; mt < 2; ++mt)
#pragma unroll
                for (int r = 0; r < 4; ++r) {
                    float v = fmaf(accx[mt][r], INV_S, acc[mt][r]);
                    mx[mt][r] = fmaxf(mx[mt][r], v);
                    sm[mt][r] += v;
                    sq[mt][r] = fmaf(v, v, sq[mt][r]);
                }
        }
        *reinterpret_cast<half8*>(&Bs[buf^1][0][u0  ][lane][0]) = g0h;
        *reinterpret_cast<half8*>(&Bs[buf^1][0][u0+1][lane][0]) = g0l;
        *reinterpret_cast<half8*>(&Bs[buf^1][1][u0  ][lane][0]) = g1h;
        *reinterpret_cast<half8*>(&Bs[buf^1][1][u0+1][lane][0]) = g1l;
        __syncthreads();
    }

    // reduce over the 16 column lanes (C/D: col=lane&15, row=kq*4+reg)
#pragma unroll
    for (int off = 8; off >= 1; off >>= 1)
#pragma unroll
        for (int mt = 0; mt < 2; ++mt)
#pragma unroll
            for (int r = 0; r < 4; ++r) {
                mx[mt][r] = fmaxf(mx[mt][r], __shfl_xor(mx[mt][r], off));
                sm[mt][r] += __shfl_xor(sm[mt][r], off);
                sq[mt][r] += __shfl_xor(sq[mt][r], off);
            }
    if (r16 == 0) {
#pragma unroll
        for (int mt = 0; mt < 2; ++mt)
#pragma unroll
            for (int r = 0; r < 4; ++r) {
                int qp = mrow + mt*16 + kq*4 + r;
                umax[b*16384 + qp]     = mx[mt][r];
                usum_b[b*16384 + qp]   = sm[mt][r];
                usumsq_b[b*16384 + qp] = sq[mt][r];
            }
    }
}

// ---------------------------------------------------------------- u_hat + fused BN3/squash (k_u absorbed) + p-partial sums.
__global__ __launch_bounds__(256) void k_uhat(const float* __restrict__ Wr,
                                              const float* __restrict__ umax,
                                              const float* __restrict__ usum_b,
                                              const float* __restrict__ usumsq_b,
                                              const float* __restrict__ g3,
                                              const float* __restrict__ be3,
                                              float* __restrict__ uhat2,
                                              float* __restrict__ s1p) {
    const int t = threadIdx.x;
    const int pblk = blockIdx.x, l = blockIdx.y;
    __shared__ float wr[4][64][20];                // [p][v][q] q-contiguous, padded
    __shared__ float us_all[32][4][16];            // [p][b][q] for this block's 32 p
    const int bb = t >> 6, v = t & 63;

    // compute this block's u slice (BN3 analytic sign-folded + squash), bit-identical to old k_u
    if (t < 128) {
        int p = t & 31, b2 = t >> 5;
        int pg = pblk * 32 + p;
        float ub[16]; float sn = 0.f;
#pragma unroll
        for (int q = 0; q < 16; ++q) {
            int qp = q * 1024 + pg;
            float s  = usum_b[qp] + usum_b[16384+qp] + usum_b[32768+qp] + usum_b[49152+qp];
            float ss = usumsq_b[qp] + usumsq_b[16384+qp] + usumsq_b[32768+qp] + usumsq_b[49152+qp];
            float g  = g3[qp];
            float sgn = (g < 0.f) ? -1.f : 1.f;
            float mean  = sgn * s * (1.f/8192.f);
            float var   = ss * (1.f/8192.f) - mean*mean;
            float scale = g * rsqrtf(var + BN_EPS);
            float val = sgn * umax[b2*16384 + qp];
            float vb = (val - mean) * scale + be3[qp];
            ub[q] = vb; sn = fmaf(vb, vb, sn);
        }
        float f = sqrtf(sn) / (1.f + sn);
#pragma unroll
        for (int q = 0; q < 16; ++q) us_all[p][b2][q] = ub[q] * f;
    }

    float s1acc = 0.f;
    for (int sub = 0; sub < 8; ++sub) {
        const int p0 = pblk * 32 + sub * 4;
        const float* src = Wr + ((size_t)l * 1024 + p0) * 1024;
        if (sub) __syncthreads();                  // LDS reuse guard
#pragma unroll
        for (int it = 0; it < 4; ++it) {
            float4 d = *(const float4*)(src + (it*256 + t) * 4);
            int vv = t >> 2, q0 = (t & 3) * 4;     // p = it
            *(float4*)&wr[it][vv][q0] = d;
        }
        __syncthreads();                           // also orders us_all init (sub==0)
#pragma unroll
        for (int p = 0; p < 4; ++p) {
            float acc = 0.f;
            const int pl = sub * 4 + p;
#pragma unroll
            for (int q4 = 0; q4 < 4; ++q4) {
                float4 wf = *(const float4*)&wr[p][v][q4*4];
                float4 uf = *(const float4*)&us_all[pl][bb][q4*4];
                acc = fmaf(wf.x, uf.x, acc);
                acc = fmaf(wf.y, uf.y, acc);
                acc = fmaf(wf.z, uf.z, acc);
                acc = fmaf(wf.w, uf.w, acc);
            }
            uhat2[(((size_t)bb * 1024 + p0 + p) * 64 + l) * 64 + v] = acc;
            s1acc += acc;
        }
    }
    s1p[(((size_t)pblk * 4 + bb) * 64 + l) * 64 + v] = s1acc;
}

// ---------------------------------------------------------------- reduce s1 partials + squash -> v1
__global__ void k_s1red(const float* __restrict__ s1p, float* __restrict__ vout) {
    const int wv = blockIdx.x;                      // b*64 + l
    const int b = wv >> 6, l = wv & 63;
    const int v = threadIdx.x;
    float acc = 0.f;
#pragma unroll
    for (int pblk = 0; pblk < 32; ++pblk)
        acc += s1p[(((size_t)pblk * 4 + b) * 64 + l) * 64 + v];
    float s = acc * (1.f/64.f);
    float sn = s * s;
#pragma unroll
    for (int off = 32; off >= 1; off >>= 1) sn += __shfl_xor(sn, off);
    vout[wv * 64 + v] = s * sqrtf(sn) / (1.f + sn);
}

// ---------------------------------------------------------------- routing pass (B or C).
__global__ __launch_bounds__(256) void k_route(const float* __restrict__ uhat2,
                                               const float* __restrict__ vin,
                                               float* __restrict__ bij,
                                               float* __restrict__ part, const int read_b) {
    const int blk = blockIdx.x;
    const int b = blk >> 7, ch = blk & 127;
    const int p0 = ch * 8;
    const int t = threadIdx.x;
    const int v = t & 63, w = t >> 6;
    __shared__ float uh[64][68];
    __shared__ float vs[64][68];
    __shared__ float bl[64];
    {
        const float* src = vin + b * 4096;
        for (int i = t; i < 1024; i += 256) {
            float4 d = *(const float4*)(src + i * 4);
            int l = i >> 4, v0 = (i & 15) * 4;
            vs[l][v0] = d.x; vs[l][v0+1] = d.y; vs[l][v0+2] = d.z; vs[l][v0+3] = d.w;
        }
    }
    float sacc[16];
#pragma unroll
    for (int j = 0; j < 16; ++j) sacc[j] = 0.f;

    for (int pp = 0; pp < 8; ++pp) {
        const int p = p0 + pp;
        __syncthreads();                            // uh/bl reuse guard (covers vs on pp=0)
        const float* src = uhat2 + ((size_t)b * 1024 + p) * 4096;   // contiguous 16 KB
        for (int i = t; i < 1024; i += 256) {
            float4 d = *(const float4*)(src + i * 4);
            int l = i >> 4, v0 = (i & 15) * 4;
            uh[l][v0] = d.x; uh[l][v0+1] = d.y; uh[l][v0+2] = d.z; uh[l][v0+3] = d.w;
        }
        __syncthreads();
#pragma unroll
        for (int i = 0; i < 16; ++i) {
            const int l = w * 16 + i;
            float prod = uh[l][v] * vs[l][v];
#pragma unroll
            for (int off = 32; off >= 1; off >>= 1) prod += __shfl_xor(prod, off);
            if (v == 0) {
                float bb = prod;
                if (read_b) bb += bij[(b * 64 + l) * 1024 + p];
                bl[l] = bb;
                if (!read_b) bij[(b * 64 + l) * 1024 + p] = bb;
            }
        }
        __syncthreads();
        // all-wave softmax over l, in registers: lane v holds x[l=v]
        float xv = bl[v];
        float m = xv;
#pragma unroll
        for (int off = 32; off >= 1; off >>= 1) m = fmaxf(m, __shfl_xor(m, off));
        float e = expf(xv - m);
        float sgm = e;
#pragma unroll
        for (int off = 32; off >= 1; off >>= 1) sgm += __shfl_xor(sgm, off);
        float c = e / sgm;                          // c[l=v]
#pragma unroll
        for (int j = 0; j < 16; ++j) {
            const int l = j * 4 + w;
            float cl = __shfl(c, l);
            sacc[j] = fmaf(cl, uh[l][v], sacc[j]);
        }
    }
#pragma unroll
    for (int j = 0; j < 16; ++j) {
        const int l = j * 4 + w;
        part[((size_t)(b * 128 + ch) * 64 + l) * 64 + v] = sacc[j];
    }
}

// ---------------------------------------------------------------- reduce partials + squash (+ presence)
__global__ void k_red_squash(const float* __restrict__ part, float* __restrict__ vout,
                             float* __restrict__ pres) {
    const int wv = blockIdx.x;                      // b*64 + l
    const int b = wv >> 6, l = wv & 63;
    const int v = threadIdx.x;
    float acc = 0.f;
    for (int ch = 0; ch < 128; ++ch) acc += part[((size_t)(b * 128 + ch) * 64 + l) * 64 + v];
    float sn = acc * acc;
#pragma unroll
    for (int off = 32; off >= 1; off >>= 1) sn += __shfl_xor(sn, off);
    vout[wv * 64 + v] = acc * sqrtf(sn) / (1.f + sn);
    if (pres != nullptr && v == 0) pres[wv] = sn / (1.f + sn);   // ||squash(s)|| = sn/(1+sn)
}

// ---------------------------------------------------------------- classifier head
__global__ void k_logits(const float* __restrict__ vj, const float* __restrict__ fcw,
                         const float* __restrict__ fcb, float* __restrict__ out) {
    int wv = blockIdx.x * 4 + (threadIdx.x >> 6);   // 0..159
    int lane = threadIdx.x & 63;
    int b = wv / 40, o = wv % 40;
    const float* xv = vj + b * 4096;
    const float* wr = fcw + (size_t)o * 4096;
    float acc = 0.f;
    for (int i = lane; i < 4096; i += 64) acc = fmaf(xv[i], wr[i], acc);
#pragma unroll
    for (int off = 32; off >= 1; off >>= 1) acc += __shfl_xor(acc, off);
    if (lane == 0) out[b * 40 + o] = acc + fcb[o];
}

extern "C" void kernel_launch(void* const* d_in, const int* in_sizes, int n_in,
                              void* d_out, int out_size, void* d_ws, size_t ws_size,
                              hipStream_t stream) {
    const float* x   = (const float*)d_in[0];
    const float* w1  = (const float*)d_in[1];
    // d_in[2] = b1: cancels under batch-norm
    const float* g1  = (const float*)d_in[3];
    const float* be1 = (const float*)d_in[4];
    const float* w2  = (const float*)d_in[5];
    // d_in[6] = b2: cancels
    const float* g2  = (const float*)d_in[7];
    const float* be2 = (const float*)d_in[8];
    const float* w3  = (const float*)d_in[9];
    // d_in[10] = b3: cancels
    const float* g3  = (const float*)d_in[11];
    const float* be3 = (const float*)d_in[12];
    const float* Wr  = (const float*)d_in[13];
    const float* fcw = (const float*)d_in[14];
    const float* fcb = (const float*)d_in[15];
    float* out = (float*)d_out;

    float* ws       = (float*)d_ws;
    float* y1       = ws;                   // [64][8192]
    float* y2       = y1 + 524288;          // [128][8192]
    float* mean1    = y2 + 1048576;         // 64
    float* inv1     = mean1 + 64;           // 64
    float* mean2    = inv1 + 64;            // 128
    float* inv2     = mean2 + 128;          // 128
    float* umax     = inv2 + 128;           // [4][16384] (sign-folded max)
    float* usum_b   = umax + 65536;         // [4][16384] per-b partials (sign-folded)
    float* usumsq_b = usum_b + 65536;       // [4][16384]
    float* u_unused = usumsq_b + 65536;     // (dead; kept for layout stability)
    float* v1       = u_unused + 65536;     // [4][64][64]
    float* v2       = v1 + 16384;
    float* vj       = v2 + 16384;
    float* bij      = vj + 16384;           // [4][64][1024]
    float* s1p      = bij + 262144;         // [32][4][64][64] (2 MB)
    float* part     = s1p + 524288;         // [4][128][64][64] (8 MB)
    float* uhat2    = part + 2097152;       // [4][1024][64][64]  (64 MB), [b][p][l][v]
    // fp16 staging buffers alias the uhat2 region: dead before k_uhat writes it.
    _Float16* w3h = (_Float16*)uhat2;       // [16384][128]
    _Float16* w3l = w3h + 2097152;
    _Float16* h2h = w3l + 2097152;          // [8192][128] (bn-major)
    _Float16* h2l = h2h + 1048576;

    k_pre<<<576, 256, 0, stream>>>(x, w1, y1, mean1, inv1, w3, g3, w3h, w3l);
    k_conv2<<<dim3(8, 32), 256, 0, stream>>>(y1, w2, mean1, inv1, g1, be1, y2);
    k_stats<<<128, 256, 0, stream>>>(y2, mean2, inv2);
    k_h2t_split<<<dim3(128, 2), 256, 0, stream>>>(y2, mean2, inv2, g2, be2, h2h, h2l);
    k_caps<<<dim3(128, 4), 256, 0, stream>>>(w3h, w3l, h2h, h2l, umax, usum_b, usumsq_b);
    k_uhat<<<dim3(32, 64), 256, 0, stream>>>(Wr, umax, usum_b, usumsq_b, g3, be3, uhat2, s1p);
    k_s1red<<<256, 64, 0, stream>>>(s1p, v1);
    k_route<<<512, 256, 0, stream>>>(uhat2, v1, bij, part, 0);
    k_red_squash<<<256, 64, 0, stream>>>(part, v2, nullptr);
    k_route<<<512, 256, 0, stream>>>(uhat2, v2, bij, part, 1);
    k_red_squash<<<256, 64, 0, stream>>>(part, vj, out + 160);
    k_logits<<<40, 256, 0, stream>>>(vj, fcw, fcb, out);
}